// Round 4
// baseline (686.465 us; speedup 1.0000x reference)
//
#include <hip/hip_runtime.h>
#include <math.h>

#define NUM_LAYERS 3
#define KCB 2048        // codebook size
#define DIM 256         // embed dim
#define NROWS 32768     // B*T
#define NQ (NROWS * DIM)

// d_ws layout: F = fp16 codebook fragments.
//   tile tn (16 cw) = 16384 B = 8 kb-blocks of [hi 1024 B | lo 1024 B]
//   within a 1024 B half: lane*16 B -> 8 halves: W[tn*16+(lane&15)][kb*32+(lane>>4)*8+j]
//   layer stride 2 MB.  wsq (fp32 ||w||^2, 3*2048) at byte offset F_BYTES.
#define F_BYTES (3u * 128u * 16384u)   // 6,291,456

// dynamic LDS partition (bytes)
#define BSH_OFF  0          // 2 bufs x [2 teams][2 tiles][16384] = 131072
#define BV_OFF   131072     // 8 waves x 32 rows x f32 = 1024
#define BI_OFF   132096     // 8 x 32 x i32 = 1024
#define BIDX_OFF 133120     // 128 x i32 = 512
#define SMEM_BYTES 133632

typedef _Float16 half8 __attribute__((ext_vector_type(8)));
typedef float   f32x4 __attribute__((ext_vector_type(4)));

// ---------------- prep: ||w||^2 (kept identical to the passing round) ----------------
__global__ void rvq_wsq(const float* __restrict__ cb, float* __restrict__ wsq)
{
    int tid = blockIdx.x * 256 + threadIdx.x;   // 0 .. 6143
    const float* p = cb + (size_t)tid * DIM;
    float s = 0.f;
    #pragma unroll
    for (int u = 0; u < 64; ++u) {
        float4 v = *(const float4*)(p + u * 4);
        s = fmaf(v.x, v.x, s); s = fmaf(v.y, v.y, s);
        s = fmaf(v.z, v.z, s); s = fmaf(v.w, v.w, s);
    }
    wsq[tid] = s;
}

// ---------------- prep: fp16 hi/lo fragment repack (identical layout) ----------------
__global__ void rvq_repack(const float* __restrict__ cb, unsigned short* __restrict__ F)
{
    int b = blockIdx.x;           // layer*1024 + tn*8 + kb
    int layer = b >> 10;
    int rem   = b & 1023;
    int tn    = rem >> 3;
    int kb    = rem & 7;
    int lane  = threadIdx.x;

    int cw = tn * 16 + (lane & 15);
    int k0 = kb * 32 + (lane >> 4) * 8;
    const float* src = cb + ((size_t)(layer * KCB + cw)) * DIM + k0;
    float4 x0 = *(const float4*)(src);
    float4 x1 = *(const float4*)(src + 4);
    float v[8] = {x0.x, x0.y, x0.z, x0.w, x1.x, x1.y, x1.z, x1.w};

    half8 hi, lo;
    #pragma unroll
    for (int j = 0; j < 8; ++j) {
        _Float16 h = (_Float16)v[j];
        hi[j] = h;
        lo[j] = (_Float16)(v[j] - (float)h);
    }
    size_t base = ((size_t)b) * 1024;   // ushort units (2048 B per (tn,kb))
    *(half8*)(F + base + lane * 8)        = hi;
    *(half8*)(F + base + 512 + lane * 8)  = lo;
}

// ---------------- main fused RVQ ----------------
// 512 thr = 8 waves: wave = rgroup(0..3)*2 + team(0..1). 128 rows/block, grid 256.
// Residual lives in out[0..NQ). B fragments staged to LDS (double-buffered, async).
__global__ __launch_bounds__(512, 2)
void rvq_main(const float* __restrict__ h,
              const float* __restrict__ cb,
              const unsigned short* __restrict__ F,
              const float* __restrict__ wsq,
              float* __restrict__ out)
{
    extern __shared__ char smem[];
    char*  Bsh     = smem + BSH_OFF;
    float* bV_sh   = (float*)(smem + BV_OFF);
    int*   bI_sh   = (int*)  (smem + BI_OFF);
    int*   bidx_sh = (int*)  (smem + BIDX_OFF);

    const int t      = threadIdx.x;
    const int lane   = t & 63;
    const int wv     = t >> 6;
    const int team   = wv & 1;        // codeword half (0: cw<1024)
    const int rgroup = wv >> 1;       // row group (32 rows each)
    const int rowB   = blockIdx.x * 128;
    const int row0w  = rowB + rgroup * 32;
    const int arow   = lane & 15;
    const int aq     = lane >> 4;

    const char* Fb_all = (const char*)F;

    for (int l = 0; l < NUM_LAYERS; ++l) {
        const float* __restrict__ rsrc = (l == 0) ? h : out;  // residual source
        const float* __restrict__ Wl   = cb + (size_t)l * KCB * DIM;
        const float* __restrict__ wql  = wsq + l * KCB;
        const char*  Fb = Fb_all + (size_t)l * 2097152;

        // ---- A-fragment build (fp16 hi/lo) + ||r||^2 ----
        half8 ahi[2][8], alo[2][8];
        float s2[2] = {0.f, 0.f};
        #pragma unroll
        for (int mi = 0; mi < 2; ++mi)
            #pragma unroll
            for (int kb = 0; kb < 8; ++kb) {
                const float* p = rsrc + (size_t)(row0w + mi * 16 + arow) * DIM + kb * 32 + aq * 8;
                float4 x0 = *(const float4*)(p);
                float4 x1 = *(const float4*)(p + 4);
                float v[8] = {x0.x, x0.y, x0.z, x0.w, x1.x, x1.y, x1.z, x1.w};
                #pragma unroll
                for (int j = 0; j < 8; ++j) {
                    _Float16 hv = (_Float16)v[j];
                    ahi[mi][kb][j] = hv;
                    alo[mi][kb][j] = (_Float16)(v[j] - (float)hv);
                    s2[mi] = fmaf(v[j], v[j], s2[mi]);
                }
            }
        #pragma unroll
        for (int mi = 0; mi < 2; ++mi) {
            s2[mi] += __shfl_xor(s2[mi], 16);
            s2[mi] += __shfl_xor(s2[mi], 32);
        }
        float rsqC[2][4];
        #pragma unroll
        for (int mi = 0; mi < 2; ++mi)
            #pragma unroll
            for (int i = 0; i < 4; ++i)
                rsqC[mi][i] = __shfl(s2[mi], aq * 4 + i, 16);

        float bestV[2][4];
        int   bestI[2][4];
        #pragma unroll
        for (int mi = 0; mi < 2; ++mi)
            #pragma unroll
            for (int i = 0; i < 4; ++i) { bestV[mi][i] = INFINITY; bestI[mi][i] = 0; }

        // ---- stage chunk 0 (async global->LDS) ----
        #pragma unroll
        for (int i = 0; i < 8; ++i) {
            int s = wv * 8 + i;
            int tm = s >> 5;
            int off = (s & 31) * 1024;
            const char* g = Fb + (size_t)tm * 1048576 + off + (size_t)lane * 16;
            char* lp = Bsh + (size_t)tm * 32768 + off + (size_t)lane * 16;
            __builtin_amdgcn_global_load_lds(
                (const __attribute__((address_space(1))) unsigned int*)g,
                (__attribute__((address_space(3))) unsigned int*)lp, 16, 0, 0);
        }
        __syncthreads();

        // ---- 32 chunks of 64 cw (2 tiles per team), dbuf ----
        for (int c = 0; c < 32; ++c) {
            const int cur = c & 1;
            if (c + 1 < 32) {
                #pragma unroll
                for (int i = 0; i < 8; ++i) {
                    int s = wv * 8 + i;
                    int tm = s >> 5;
                    int off = (s & 31) * 1024;
                    const char* g = Fb + (size_t)tm * 1048576 + (size_t)(c + 1) * 32768 + off + (size_t)lane * 16;
                    char* lp = Bsh + (size_t)(1 - cur) * 65536 + (size_t)tm * 32768 + off + (size_t)lane * 16;
                    __builtin_amdgcn_global_load_lds(
                        (const __attribute__((address_space(1))) unsigned int*)g,
                        (__attribute__((address_space(3))) unsigned int*)lp, 16, 0, 0);
                }
            }
            #pragma unroll
            for (int ti = 0; ti < 2; ++ti) {
                const char* base = Bsh + (size_t)cur * 65536 + (size_t)team * 32768 + (size_t)ti * 16384;
                f32x4 acc[2][2];
                const f32x4 z = {0.f, 0.f, 0.f, 0.f};
                acc[0][0] = z; acc[0][1] = z; acc[1][0] = z; acc[1][1] = z;
                #pragma unroll
                for (int kb = 0; kb < 8; ++kb) {
                    half8 bhi = *(const half8*)(base + kb * 2048 + lane * 16);
                    half8 blo = *(const half8*)(base + kb * 2048 + 1024 + lane * 16);
                    const int p = kb & 1;
                    acc[0][p] = __builtin_amdgcn_mfma_f32_16x16x32_f16(ahi[0][kb], bhi, acc[0][p], 0, 0, 0);
                    acc[1][p] = __builtin_amdgcn_mfma_f32_16x16x32_f16(ahi[1][kb], bhi, acc[1][p], 0, 0, 0);
                    acc[0][p] = __builtin_amdgcn_mfma_f32_16x16x32_f16(alo[0][kb], bhi, acc[0][p], 0, 0, 0);
                    acc[1][p] = __builtin_amdgcn_mfma_f32_16x16x32_f16(alo[1][kb], bhi, acc[1][p], 0, 0, 0);
                    acc[0][p] = __builtin_amdgcn_mfma_f32_16x16x32_f16(ahi[0][kb], blo, acc[0][p], 0, 0, 0);
                    acc[1][p] = __builtin_amdgcn_mfma_f32_16x16x32_f16(ahi[1][kb], blo, acc[1][p], 0, 0, 0);
                }
                const int col = team * 1024 + (c * 2 + ti) * 16 + arow;
                const float wq = wql[col];
                #pragma unroll
                for (int mi = 0; mi < 2; ++mi)
                    #pragma unroll
                    for (int i = 0; i < 4; ++i) {
                        float cc = acc[mi][0][i] + acc[mi][1][i];
                        float dist = (rsqC[mi][i] - 2.f * cc) + wq;
                        if (dist < bestV[mi][i]) { bestV[mi][i] = dist; bestI[mi][i] = col; }
                    }
            }
            __syncthreads();   // drains prefetch (vmcnt) + releases cur buf
        }

        // ---- argmin: reduce across the 16 lanes sharing each row-quad ----
        #pragma unroll
        for (int mi = 0; mi < 2; ++mi)
            #pragma unroll
            for (int i = 0; i < 4; ++i) {
                float bv = bestV[mi][i]; int bi = bestI[mi][i];
                #pragma unroll
                for (int s = 8; s; s >>= 1) {
                    float ov = __shfl_xor(bv, s, 16);
                    int   oi = __shfl_xor(bi, s, 16);
                    if (ov < bv || (ov == bv && oi < bi)) { bv = ov; bi = oi; }
                }
                bestV[mi][i] = bv; bestI[mi][i] = bi;
            }
        if (arow == 0) {
            #pragma unroll
            for (int mi = 0; mi < 2; ++mi)
                #pragma unroll
                for (int i = 0; i < 4; ++i) {
                    bV_sh[wv * 32 + mi * 16 + aq * 4 + i] = bestV[mi][i];
                    bI_sh[wv * 32 + mi * 16 + aq * 4 + i] = bestI[mi][i];
                }
        }
        __syncthreads();

        // ---- combine the two cw-teams per row, write index ----
        if (t < 128) {
            int rg = t >> 5, rl = t & 31;
            float v0 = bV_sh[(rg * 2 + 0) * 32 + rl]; int i0 = bI_sh[(rg * 2 + 0) * 32 + rl];
            float v1 = bV_sh[(rg * 2 + 1) * 32 + rl]; int i1 = bI_sh[(rg * 2 + 1) * 32 + rl];
            int bi = (v1 < v0 || (v1 == v0 && i1 < i0)) ? i1 : i0;
            bidx_sh[t] = bi;
            out[NQ + (size_t)l * NROWS + rowB + t] = (float)bi;
        }
        __syncthreads();

        // ---- residual update (rows block-private, via global) ----
        {
            int row = t >> 2, q4 = t & 3;
            const int bi = bidx_sh[row];
            const float* wrow = Wl + (size_t)bi * DIM + q4 * 64;
            const float* rr = rsrc + (size_t)(rowB + row) * DIM + q4 * 64;
            float* rw = out + (size_t)(rowB + row) * DIM + q4 * 64;
            if (l < NUM_LAYERS - 1) {
                #pragma unroll
                for (int u = 0; u < 16; ++u) {
                    float4 r = *(const float4*)(rr + u * 4);
                    float4 w = *(const float4*)(wrow + u * 4);
                    float4 o; o.x = r.x - w.x; o.y = r.y - w.y; o.z = r.z - w.z; o.w = r.w - w.w;
                    *(float4*)(rw + u * 4) = o;
                }
            } else {
                const float* hh = h + (size_t)(rowB + row) * DIM + q4 * 64;
                #pragma unroll
                for (int u = 0; u < 16; ++u) {
                    float4 r = *(const float4*)(rr + u * 4);
                    float4 w = *(const float4*)(wrow + u * 4);
                    float4 hv = *(const float4*)(hh + u * 4);
                    float4 o;
                    o.x = hv.x - (r.x - w.x); o.y = hv.y - (r.y - w.y);
                    o.z = hv.z - (r.z - w.z); o.w = hv.w - (r.w - w.w);
                    *(float4*)(rw + u * 4) = o;
                }
            }
        }
        __threadfence();     // flush stores + invalidate L1 before next layer's reads
        __syncthreads();
    }
}

extern "C" void kernel_launch(void* const* d_in, const int* in_sizes, int n_in,
                              void* d_out, int out_size, void* d_ws, size_t ws_size,
                              hipStream_t stream) {
    const float* h  = (const float*)d_in[0];
    const float* cb = (const float*)d_in[1];
    float* out = (float*)d_out;
    unsigned short* F = (unsigned short*)d_ws;
    float* wsq = (float*)((char*)d_ws + F_BYTES);

    hipFuncSetAttribute((const void*)rvq_main,
                        hipFuncAttributeMaxDynamicSharedMemorySize, SMEM_BYTES);

    rvq_wsq   <<<dim3(24),   dim3(256), 0, stream>>>(cb, wsq);
    rvq_repack<<<dim3(3072), dim3(64),  0, stream>>>(cb, F);
    rvq_main  <<<dim3(NROWS / 128), dim3(512), SMEM_BYTES, stream>>>(h, cb, F, wsq, out);
}

// Round 5
// 413.359 us; speedup vs baseline: 1.6607x; 1.6607x over previous
//
#include <hip/hip_runtime.h>
#include <math.h>

#define NUM_LAYERS 3
#define KCB 2048        // codebook size
#define DIM 256         // embed dim
#define NROWS 32768     // B*T
#define NQ (NROWS * DIM)

// d_ws layout: F = fp16 codebook fragments.
//   tile tn (16 cw) = 16384 B = 8 kb-blocks of [hi 1024 B | lo 1024 B]
//   within a 1024 B half: lane*16 B -> 8 halves: W[tn*16+(lane&15)][kb*32+(lane>>4)*8+j]
//   layer stride 2 MB.  wsq (fp32 ||w||^2, 3*2048) at byte offset F_BYTES.
#define F_BYTES (3u * 128u * 16384u)   // 6,291,456

// dynamic LDS partition (bytes)
#define BSH_OFF  0          // 2 bufs x [2 teams][2 tiles][16384] = 131072
#define BV_OFF   131072     // 8 waves x 32 rows x f32 = 1024
#define BI_OFF   132096     // 8 x 32 x i32 = 1024
#define BIDX_OFF 133120     // 128 x i32 = 512
#define SMEM_BYTES 133632

typedef _Float16 half8 __attribute__((ext_vector_type(8)));
typedef float   f32x4 __attribute__((ext_vector_type(4)));

// ---------------- prep: ||w||^2 (unchanged, verified) ----------------
__global__ void rvq_wsq(const float* __restrict__ cb, float* __restrict__ wsq)
{
    int tid = blockIdx.x * 256 + threadIdx.x;   // 0 .. 6143
    const float* p = cb + (size_t)tid * DIM;
    float s = 0.f;
    #pragma unroll
    for (int u = 0; u < 64; ++u) {
        float4 v = *(const float4*)(p + u * 4);
        s = fmaf(v.x, v.x, s); s = fmaf(v.y, v.y, s);
        s = fmaf(v.z, v.z, s); s = fmaf(v.w, v.w, s);
    }
    wsq[tid] = s;
}

// ---------------- prep: fp16 hi/lo fragment repack (unchanged, verified) ----------------
__global__ void rvq_repack(const float* __restrict__ cb, unsigned short* __restrict__ F)
{
    int b = blockIdx.x;           // layer*1024 + tn*8 + kb
    int layer = b >> 10;
    int rem   = b & 1023;
    int tn    = rem >> 3;
    int kb    = rem & 7;
    int lane  = threadIdx.x;

    int cw = tn * 16 + (lane & 15);
    int k0 = kb * 32 + (lane >> 4) * 8;
    const float* src = cb + ((size_t)(layer * KCB + cw)) * DIM + k0;
    float4 x0 = *(const float4*)(src);
    float4 x1 = *(const float4*)(src + 4);
    float v[8] = {x0.x, x0.y, x0.z, x0.w, x1.x, x1.y, x1.z, x1.w};

    half8 hi, lo;
    #pragma unroll
    for (int j = 0; j < 8; ++j) {
        _Float16 h = (_Float16)v[j];
        hi[j] = h;
        lo[j] = (_Float16)(v[j] - (float)h);
    }
    size_t base = ((size_t)b) * 1024;   // ushort units (2048 B per (tn,kb))
    *(half8*)(F + base + lane * 8)        = hi;
    *(half8*)(F + base + 512 + lane * 8)  = lo;
}

// ---------------- async stage of one 64 KB chunk (64 cw, hi+lo) ----------------
__device__ __forceinline__ void stage_chunk(const char* Fb, char* Bsh,
                                            int c, int buf, int wv, int lane)
{
    #pragma unroll
    for (int i = 0; i < 8; ++i) {
        int s = wv * 8 + i;
        int tm = s >> 5;
        int off = (s & 31) * 1024;
        const char* g = Fb + (size_t)tm * 1048576 + (size_t)c * 32768 + off + (size_t)lane * 16;
        char* lp = Bsh + (size_t)buf * 65536 + (size_t)tm * 32768 + off + (size_t)lane * 16;
        __builtin_amdgcn_global_load_lds(
            (const __attribute__((address_space(1))) unsigned int*)g,
            (__attribute__((address_space(3))) unsigned int*)lp, 16, 0, 0);
    }
}

// ---------------- main fused RVQ ----------------
// 512 thr = 8 waves: wave = rgroup(0..3)*2 + team(0..1). 128 rows/block, grid 256
// (1 block/CU, 2 waves/SIMD). Residual lives in registers as fp16 hi/lo fragments.
__global__ __launch_bounds__(512, 2)
void rvq_main(const float* __restrict__ h,
              const float* __restrict__ cb,
              const unsigned short* __restrict__ F,
              const float* __restrict__ wsq,
              float* __restrict__ out)
{
    extern __shared__ char smem[];
    char*  Bsh     = smem + BSH_OFF;
    float* bV_sh   = (float*)(smem + BV_OFF);
    int*   bI_sh   = (int*)  (smem + BI_OFF);
    int*   bidx_sh = (int*)  (smem + BIDX_OFF);

    const int t      = threadIdx.x;
    const int lane   = t & 63;
    const int wv     = t >> 6;
    const int team   = wv & 1;        // codeword half (0: cw<1024)
    const int rgroup = wv >> 1;       // row group (32 rows each)
    const int rowB   = blockIdx.x * 128;
    const int row0w  = rowB + rgroup * 32;
    const int arow   = lane & 15;
    const int aq     = lane >> 4;

    // ---- residual fragments (fp16 hi/lo) + per-lane partial ||r||^2, from h ----
    half8 ahi[2][8], alo[2][8];
    float s2[2];
    #pragma unroll
    for (int mi = 0; mi < 2; ++mi) {
        s2[mi] = 0.f;
        #pragma unroll
        for (int kb = 0; kb < 8; ++kb) {
            const float* p = h + (size_t)(row0w + mi * 16 + arow) * DIM + kb * 32 + aq * 8;
            float4 x0 = *(const float4*)(p);
            float4 x1 = *(const float4*)(p + 4);
            float v[8] = {x0.x, x0.y, x0.z, x0.w, x1.x, x1.y, x1.z, x1.w};
            #pragma unroll
            for (int j = 0; j < 8; ++j) {
                _Float16 hv = (_Float16)v[j];
                ahi[mi][kb][j] = hv;
                alo[mi][kb][j] = (_Float16)(v[j] - (float)hv);
                s2[mi] = fmaf(v[j], v[j], s2[mi]);
            }
        }
    }

    // ---- prefetch layer 0, chunk 0 into buf 0 ----
    stage_chunk((const char*)F, Bsh, 0, 0, wv, lane);

    for (int l = 0; l < NUM_LAYERS; ++l) {
        const float* __restrict__ Wl  = cb + (size_t)l * KCB * DIM;
        const float* __restrict__ wql = wsq + l * KCB;
        const char*  Fb = (const char*)F + (size_t)l * 2097152;

        // ---- reduce ||r||^2 across the 4 aq-lanes per row; broadcast to C layout ----
        float a0 = s2[0], a1 = s2[1];
        a0 += __shfl_xor(a0, 16); a0 += __shfl_xor(a0, 32);
        a1 += __shfl_xor(a1, 16); a1 += __shfl_xor(a1, 32);
        float rsqC[2][4];
        #pragma unroll
        for (int i = 0; i < 4; ++i) {
            rsqC[0][i] = __shfl(a0, aq * 4 + i, 16);
            rsqC[1][i] = __shfl(a1, aq * 4 + i, 16);
        }

        float bestV[2][4];
        int   bestI[2][4];
        #pragma unroll
        for (int mi = 0; mi < 2; ++mi)
            #pragma unroll
            for (int i = 0; i < 4; ++i) { bestV[mi][i] = INFINITY; bestI[mi][i] = 0; }

        __syncthreads();   // chunk-0 staging complete (drains vmcnt)

        // ---- 32 chunks of 64 cw (2 tiles per team), double-buffered ----
        for (int c = 0; c < 32; ++c) {
            const int cur = c & 1;
            if (c + 1 < 32) stage_chunk(Fb, Bsh, c + 1, 1 - cur, wv, lane);

            #pragma unroll
            for (int ti = 0; ti < 2; ++ti) {
                const char* base = Bsh + (size_t)cur * 65536 + (size_t)team * 32768 + (size_t)ti * 16384;
                f32x4 acc[2][2];
                const f32x4 z = {0.f, 0.f, 0.f, 0.f};
                acc[0][0] = z; acc[0][1] = z; acc[1][0] = z; acc[1][1] = z;
                #pragma unroll
                for (int kb = 0; kb < 8; ++kb) {
                    half8 bhi = *(const half8*)(base + kb * 2048 + lane * 16);
                    half8 blo = *(const half8*)(base + kb * 2048 + 1024 + lane * 16);
                    const int p = kb & 1;
                    acc[0][p] = __builtin_amdgcn_mfma_f32_16x16x32_f16(ahi[0][kb], bhi, acc[0][p], 0, 0, 0);
                    acc[1][p] = __builtin_amdgcn_mfma_f32_16x16x32_f16(ahi[1][kb], bhi, acc[1][p], 0, 0, 0);
                    acc[0][p] = __builtin_amdgcn_mfma_f32_16x16x32_f16(alo[0][kb], bhi, acc[0][p], 0, 0, 0);
                    acc[1][p] = __builtin_amdgcn_mfma_f32_16x16x32_f16(alo[1][kb], bhi, acc[1][p], 0, 0, 0);
                    acc[0][p] = __builtin_amdgcn_mfma_f32_16x16x32_f16(ahi[0][kb], blo, acc[0][p], 0, 0, 0);
                    acc[1][p] = __builtin_amdgcn_mfma_f32_16x16x32_f16(ahi[1][kb], blo, acc[1][p], 0, 0, 0);
                }
                const int col = team * 1024 + (c * 2 + ti) * 16 + arow;
                const float wq = wql[col];
                #pragma unroll
                for (int mi = 0; mi < 2; ++mi)
                    #pragma unroll
                    for (int i = 0; i < 4; ++i) {
                        float cc = acc[mi][0][i] + acc[mi][1][i];
                        float dist = (rsqC[mi][i] - 2.f * cc) + wq;
                        if (dist < bestV[mi][i]) { bestV[mi][i] = dist; bestI[mi][i] = col; }
                    }
            }
            __syncthreads();   // releases cur buf; drains next-chunk prefetch
        }

        // ---- argmin: reduce across the 16 arow-lanes sharing each row-quad ----
        #pragma unroll
        for (int mi = 0; mi < 2; ++mi)
            #pragma unroll
            for (int i = 0; i < 4; ++i) {
                float bv = bestV[mi][i]; int bi = bestI[mi][i];
                #pragma unroll
                for (int s = 8; s; s >>= 1) {
                    float ov = __shfl_xor(bv, s, 16);
                    int   oi = __shfl_xor(bi, s, 16);
                    if (ov < bv || (ov == bv && oi < bi)) { bv = ov; bi = oi; }
                }
                bestV[mi][i] = bv; bestI[mi][i] = bi;
            }
        if (arow == 0) {
            #pragma unroll
            for (int mi = 0; mi < 2; ++mi)
                #pragma unroll
                for (int i = 0; i < 4; ++i) {
                    bV_sh[wv * 32 + mi * 16 + aq * 4 + i] = bestV[mi][i];
                    bI_sh[wv * 32 + mi * 16 + aq * 4 + i] = bestI[mi][i];
                }
        }
        __syncthreads();

        // ---- combine the two cw-teams per row, write index ----
        if (t < 128) {
            int rg = t >> 5, rl = t & 31;
            float v0 = bV_sh[(rg * 2 + 0) * 32 + rl]; int i0 = bI_sh[(rg * 2 + 0) * 32 + rl];
            float v1 = bV_sh[(rg * 2 + 1) * 32 + rl]; int i1 = bI_sh[(rg * 2 + 1) * 32 + rl];
            int bi = (v1 < v0 || (v1 == v0 && i1 < i0)) ? i1 : i0;
            bidx_sh[t] = bi;
            out[NQ + (size_t)l * NROWS + rowB + t] = (float)bi;
        }
        // prefetch next layer's chunk 0 (independent of bidx) into buf 0
        if (l < NUM_LAYERS - 1)
            stage_chunk(Fb + 2097152, Bsh, 0, 0, wv, lane);
        __syncthreads();   // bidx_sh visible

        if (l < NUM_LAYERS - 1) {
            // ---- residual update in registers: r <- (hi+lo) - w, re-split ----
            #pragma unroll
            for (int mi = 0; mi < 2; ++mi) {
                const int bi = bidx_sh[rgroup * 32 + mi * 16 + arow];
                const float* wrow = Wl + (size_t)bi * DIM;
                float ns = 0.f;
                #pragma unroll
                for (int kb = 0; kb < 8; ++kb) {
                    const float* wp = wrow + kb * 32 + aq * 8;
                    float4 w0 = *(const float4*)(wp);
                    float4 w1 = *(const float4*)(wp + 4);
                    float wv8[8] = {w0.x, w0.y, w0.z, w0.w, w1.x, w1.y, w1.z, w1.w};
                    #pragma unroll
                    for (int j = 0; j < 8; ++j) {
                        float r = ((float)ahi[mi][kb][j] + (float)alo[mi][kb][j]) - wv8[j];
                        _Float16 hv = (_Float16)r;
                        ahi[mi][kb][j] = hv;
                        alo[mi][kb][j] = (_Float16)(r - (float)hv);
                        ns = fmaf(r, r, ns);
                    }
                }
                s2[mi] = ns;
            }
        } else {
            // ---- final: out = h - (r2 - w3); team handles mi == team ----
            const int mi  = team;
            const int row = row0w + mi * 16 + arow;
            const int bi  = bidx_sh[rgroup * 32 + mi * 16 + arow];
            const float* wrow = Wl + (size_t)bi * DIM;
            #pragma unroll
            for (int kb = 0; kb < 8; ++kb) {
                const float* wp = wrow + kb * 32 + aq * 8;
                const float* hp = h + (size_t)row * DIM + kb * 32 + aq * 8;
                float4 w0 = *(const float4*)(wp);
                float4 w1 = *(const float4*)(wp + 4);
                float4 h0 = *(const float4*)(hp);
                float4 h1 = *(const float4*)(hp + 4);
                float wv8[8] = {w0.x, w0.y, w0.z, w0.w, w1.x, w1.y, w1.z, w1.w};
                float hv8[8] = {h0.x, h0.y, h0.z, h0.w, h1.x, h1.y, h1.z, h1.w};
                float o[8];
                #pragma unroll
                for (int j = 0; j < 8; ++j) {
                    float r = ((float)ahi[mi][kb][j] + (float)alo[mi][kb][j]) - wv8[j];
                    o[j] = hv8[j] - r;
                }
                float* op = out + (size_t)row * DIM + kb * 32 + aq * 8;
                *(float4*)(op)     = make_float4(o[0], o[1], o[2], o[3]);
                *(float4*)(op + 4) = make_float4(o[4], o[5], o[6], o[7]);
            }
        }
    }
}

extern "C" void kernel_launch(void* const* d_in, const int* in_sizes, int n_in,
                              void* d_out, int out_size, void* d_ws, size_t ws_size,
                              hipStream_t stream) {
    const float* h  = (const float*)d_in[0];
    const float* cb = (const float*)d_in[1];
    float* out = (float*)d_out;
    unsigned short* F = (unsigned short*)d_ws;
    float* wsq = (float*)((char*)d_ws + F_BYTES);

    hipFuncSetAttribute((const void*)rvq_main,
                        hipFuncAttributeMaxDynamicSharedMemorySize, SMEM_BYTES);

    rvq_wsq   <<<dim3(24),   dim3(256), 0, stream>>>(cb, wsq);
    rvq_repack<<<dim3(3072), dim3(64),  0, stream>>>(cb, F);
    rvq_main  <<<dim3(NROWS / 128), dim3(512), SMEM_BYTES, stream>>>(h, cb, F, wsq, out);
}